// Round 1
// baseline (89.406 us; speedup 1.0000x reference)
//
#include <hip/hip_runtime.h>

#define S 2000
#define P 2500
#define R 5

__device__ __forceinline__ void flags_for(
    float fx, float fy, float scale, float ptx, float pty,
    float lastx, float lasty, float psum,
    float& gx, float& gy, int& fl)
{
    // tol = ATOL + RTOL*|f| with separate rounding (match numpy, no fma)
    float tolx = __fadd_rn(0.01f, __fmul_rn(1e-5f, __builtin_fabsf(fx)));
    float toly = __fadd_rn(0.01f, __fmul_rn(1e-5f, __builtin_fabsf(fy)));
    bool cx = false, cy = false;
#pragma unroll
    for (int k = -2; k <= 2; ++k) {
        float ks = (float)k * scale;   // exact: k in {-2..2}
        float lx = ks + ptx;           // one rounding (fma-safe since ks exact)
        float ly = ks + pty;
        cx = cx || (__builtin_fabsf(lx - fx) <= tolx);
        cy = cy || (__builtin_fabsf(ly - fy) <= toly);
    }
    float fsum = fx + fy;
    bool below = fsum < psum;
    bool above = fsum > psum;
    bool condx = cx && (fy <= lasty);
    bool condy = cy && (fx <= lastx);
    bool ux = condx && above;
    bool lxf = condx && below;
    bool uy = condy && above;
    bool lyf = condy && below;
    gx = ux ? 1.0f : (lxf ? -1.0f : 0.0f);
    gy = uy ? 1.0f : (lyf ? -1.0f : 0.0f);
    fl |= (ux ? 1 : 0) | (lxf ? 2 : 0) | (uy ? 4 : 0) | (lyf ? 8 : 0);
}

__global__ __launch_bounds__(256) void grad_kernel(
    const float* __restrict__ filtration,   // (S,2) interleaved fx,fy
    const float* __restrict__ bars0,        // (P,R)
    const float* __restrict__ bars1,        // (P,R)
    const float* __restrict__ sample_pts,   // (P,2)
    float* __restrict__ gm0, float* __restrict__ gc0,
    float* __restrict__ gm1, float* __restrict__ gc1)
{
    int bid = blockIdx.x;
    int h = bid / (P * R);
    int rem = bid - h * (P * R);
    int r = rem / P;
    int p = rem - r * P;

    const float* bars = h ? bars1 : bars0;
    float* gm = h ? gm1 : gm0;
    float* gc = h ? gc1 : gc0;

    float bar = bars[p * R + r];
    float scale = bar + 0.01f;               // GRID_RES
    float ptx = sample_pts[2 * p];
    float pty = sample_pts[2 * p + 1];
    float lastx = 2.0f * scale + ptx;        // line[..., -1], exact mul
    float lasty = 2.0f * scale + pty;
    float psum = ptx + pty;

    // output row: gm[(r,p), 2s+c]; two s per float4
    float4* gmrow = (float4*)(gm + ((size_t)r * P + p) * (size_t)(2 * S));
    const float4* filt4 = (const float4*)filtration;   // (S/2) x {fx0,fy0,fx1,fy1}

    __shared__ int bflags;
    if (threadIdx.x == 0) bflags = 0;
    __syncthreads();

    int myflags = 0;
    for (int j = threadIdx.x; j < S / 2; j += blockDim.x) {
        float4 f = filt4[j];
        float4 o;
        flags_for(f.x, f.y, scale, ptx, pty, lastx, lasty, psum, o.x, o.y, myflags);
        flags_for(f.z, f.w, scale, ptx, pty, lastx, lasty, psum, o.z, o.w, myflags);
        gmrow[j] = o;
    }

    // block-level "any" reduce of the 4 flag bits
    int wf = 0;
    wf |= __any(myflags & 1) ? 1 : 0;
    wf |= __any(myflags & 2) ? 2 : 0;
    wf |= __any(myflags & 4) ? 4 : 0;
    wf |= __any(myflags & 8) ? 8 : 0;
    if ((threadIdx.x & 63) == 0 && wf) atomicOr(&bflags, wf);
    __syncthreads();

    if (threadIdx.x == 0) {
        int bf = bflags;
        float cxv = (bf & 1) ? -1.0f : ((bf & 2) ? 1.0f : 0.0f);
        float cyv = (bf & 4) ? -1.0f : ((bf & 8) ? 1.0f : 0.0f);
        size_t base = ((size_t)r * P + p) * 2;
        gc[base] = cxv;
        gc[base + 1] = cyv;
    }
}

__global__ __launch_bounds__(256) void copy_out_kernel(
    const float* __restrict__ b0, const float* __restrict__ b1,
    float* __restrict__ out)
{
    int i = blockIdx.x * blockDim.x + threadIdx.x;
    if (i < P * R) {
        out[i] = b0[i];
        out[P * R + i] = b1[i];
    }
}

extern "C" void kernel_launch(void* const* d_in, const int* in_sizes, int n_in,
                              void* d_out, int out_size, void* d_ws, size_t ws_size,
                              hipStream_t stream) {
    const float* filtration = (const float*)d_in[0];   // (2000,2)
    const float* bars_h0    = (const float*)d_in[1];   // (2500,5)
    const float* bars_h1    = (const float*)d_in[2];   // (2500,5)
    const float* sample_pts = (const float*)d_in[3];   // (2500,2)

    float* out = (float*)d_out;
    float* o_stack = out;                                 // 2*P*R      = 25000
    float* gm0     = o_stack + (size_t)2 * P * R;         // R*P*2S     = 50,000,000
    float* gc0     = gm0 + (size_t)R * P * 2 * S;         // R*P*2      = 25000
    float* gm1     = gc0 + (size_t)R * P * 2;             // 50,000,000
    float* gc1     = gm1 + (size_t)R * P * 2 * S;         // 25000

    copy_out_kernel<<<(P * R + 255) / 256, 256, 0, stream>>>(bars_h0, bars_h1, o_stack);
    grad_kernel<<<2 * P * R, 256, 0, stream>>>(filtration, bars_h0, bars_h1, sample_pts,
                                               gm0, gc0, gm1, gc1);
}